// Round 10
// baseline (285.340 us; speedup 1.0000x reference)
//
#include <hip/hip_runtime.h>

#define N_NODES 100000
#define N_EDGES 1000000
#define DEG_CAP 64
#define OVF_CAP 4096
#define RSTRIDE 100352   // N_NODES rounded up to 512

typedef __attribute__((ext_vector_type(8))) short bf16x8;
typedef __attribute__((ext_vector_type(4))) float f32x4;

__device__ __forceinline__ unsigned short f2bf(float f) {
    unsigned u = __float_as_uint(f);
    return (unsigned short)((u + 0x7FFF + ((u >> 16) & 1)) >> 16);
}
__device__ __forceinline__ float bf2f(unsigned short b) {
    return __uint_as_float(((unsigned)b) << 16);
}
__device__ __forceinline__ float bflo(unsigned u) {
    return __uint_as_float(u << 16);
}
__device__ __forceinline__ float bfhi(unsigned u) {
    return __uint_as_float(u & 0xffff0000u);
}

// ws layout (4B units):
//   counts_r : int [0,        802816)
//   bases_r  : int [802816,  1605632)
//   counts   : int [1605632, 1705984)
//   pos16    : u16 [1705984, 2205984)
//   ovfc     : int [2205984]
//   ovf      : int [2206048, 2214240)
//   Bf1      : s16 [2214240, 2230624)   32768 halfs (frag-ordered hi/lo)
//   Bf2      : s16 [2230624, 2247008)
//   slots    : int [2247008, 8647008)   N*64
//   xh       : u16 [8647008, 11847008)  N*64 hi plane
//   xl       : u16 [11847008, 15047008) N*64 lo plane
//   meanh    : u16 [15047008, 18247008) N*64; reused as p_bf after l1
//   meanl    : u16 [18247008, 21447008)
//   hh       : u16 [21447008, 27847008) N*128 hi plane
//   hl       : u16 [27847008, 34247008) N*128 lo plane
//   qb       : u16 [34247008, 37447008) N*64 bf16
// total 37,447,008 * 4B = 149.8 MB

// Merged zero + weight-split + x->split-planes.
__global__ __launch_bounds__(256) void prep_kernel(
        const float4* __restrict__ x4,
        ushort4* __restrict__ xh4, ushort4* __restrict__ xl4,
        const float* __restrict__ W1l, const float* __restrict__ W1r,
        const float* __restrict__ W2l, const float* __restrict__ W2r,
        short* __restrict__ Bf1, short* __restrict__ Bf2,
        int4* __restrict__ counts_r4, int* __restrict__ ovfc) {
    int i = blockIdx.x * blockDim.x + threadIdx.x;
    if (i < (8 * RSTRIDE) / 4) counts_r4[i] = make_int4(0, 0, 0, 0);
    if (i == 0) *ovfc = 0;
    if (i < 32768) {
        int g = i >> 14;
        int e = i & 16383;
        int k = e >> 7;
        int n = e & 127;
        float v;
        if (g == 0) v = (k < 64) ? W1l[k * 128 + n] : W1r[(k - 64) * 128 + n];
        else        v = (n < 64) ? W2l[k * 64 + n]  : W2r[k * 64 + (n - 64)];
        unsigned short hb = f2bf(v);
        unsigned short lb = f2bf(v - bf2f(hb));
        int c = n >> 4, kc = k >> 5;
        int lane = (((k >> 3) & 3) << 4) | (n & 15);
        int j = k & 7;
        short* base = g ? Bf2 : Bf1;
        base[((c * 4 + kc) * 2 + 0) * 512 + lane * 8 + j] = (short)hb;
        base[((c * 4 + kc) * 2 + 1) * 512 + lane * 8 + j] = (short)lb;
    }
    if (i < N_NODES * 16) {
        float4 v = x4[i];
        ushort4 oh, ol;
        oh.x = f2bf(v.x); ol.x = f2bf(v.x - bf2f(oh.x));
        oh.y = f2bf(v.y); ol.y = f2bf(v.y - bf2f(oh.y));
        oh.z = f2bf(v.z); ol.z = f2bf(v.z - bf2f(oh.z));
        oh.w = f2bf(v.w); ol.w = f2bf(v.w - bf2f(oh.w));
        xh4[i] = oh;
        xl4[i] = ol;
    }
}

// Phase 1: replicated histogram (replica = XCD id; stash (replica,pos) u16).
__global__ __launch_bounds__(256) void hist_kernel(
        const int* __restrict__ ei, int* __restrict__ counts_r,
        unsigned short* __restrict__ pos16) {
    int e = blockIdx.x * blockDim.x + threadIdx.x;
    if (e >= N_EDGES) return;
    unsigned xcc;
    asm volatile("s_getreg_b32 %0, hwreg(HW_REG_XCC_ID)" : "=s"(xcc));
    int r = xcc & 7;
    int d = ei[N_EDGES + e];
    int p = atomicAdd(&counts_r[r * RSTRIDE + d], 1);
    if (p > 8191) p = 8191;
    pos16[e] = (unsigned short)((r << 13) | p);
}

// Phase 2: per-node prefix over the 8 replicas.
__global__ __launch_bounds__(256) void scan_kernel(
        const int* __restrict__ counts_r, int* __restrict__ bases_r,
        int* __restrict__ counts) {
    int d = blockIdx.x * blockDim.x + threadIdx.x;
    if (d >= N_NODES) return;
    int base = 0;
#pragma unroll
    for (int r = 0; r < 8; ++r) {
        bases_r[r * RSTRIDE + d] = base;
        base += counts_r[r * RSTRIDE + d];
    }
    counts[d] = base;
}

// Phase 3: atomic-free slot fill; overflow funnel.
__global__ __launch_bounds__(256) void fill_kernel(
        const int* __restrict__ ei, const unsigned short* __restrict__ pos16,
        const int* __restrict__ bases_r, int* __restrict__ slots,
        int* __restrict__ ovfc, int* __restrict__ ovf) {
    int e = blockIdx.x * blockDim.x + threadIdx.x;
    if (e >= N_EDGES) return;
    int s = ei[e];
    int d = ei[N_EDGES + e];
    unsigned pk = pos16[e];
    int r = pk >> 13;
    int p = pk & 8191;
    int pos = bases_r[r * RSTRIDE + d] + p;
    if (p < 8191 && pos < DEG_CAP) {
        slots[d * DEG_CAP + pos] = s;
    } else {
        int o = atomicAdd(ovfc, 1);
        if (o < OVF_CAP) { ovf[o * 2] = s; ovf[o * 2 + 1] = d; }
    }
}

// One wave per node; 4 neighbor rows per dwordx2 load; butterfly reduce.
// Writes the MEAN as split bf16 planes (RTN hi + RTN residual).
__global__ __launch_bounds__(256) void gather_bf_kernel(
        const unsigned short* __restrict__ feat, const int* __restrict__ counts,
        const int* __restrict__ slots,
        unsigned short* __restrict__ mh, unsigned short* __restrict__ ml) {
    int wid = blockIdx.x * 4 + (threadIdx.x >> 6);
    int l = threadIdx.x & 63;
    if (wid >= N_NODES) return;
    int deg = counts[wid];
    int dcap = min(deg, DEG_CAP);
    int ids = slots[wid * DEG_CAP + l];
    const int grp = l >> 4;
    const int fb = (l & 15) * 4;
    float s0 = 0.f, s1 = 0.f, s2 = 0.f, s3 = 0.f;
    int j = 0;
    for (; j + 8 <= dcap; j += 8) {
        int sA = __shfl(ids, j + grp);
        int sB = __shfl(ids, j + 4 + grp);
        uint2 uA = *(const uint2*)(feat + sA * 64 + fb);
        uint2 uB = *(const uint2*)(feat + sB * 64 + fb);
        s0 += bflo(uA.x) + bflo(uB.x);
        s1 += bfhi(uA.x) + bfhi(uB.x);
        s2 += bflo(uA.y) + bflo(uB.y);
        s3 += bfhi(uA.y) + bfhi(uB.y);
    }
    for (; j < dcap; j += 4) {
        int nb = j + grp;
        bool v = nb < dcap;
        int s = __shfl(ids, v ? nb : 0);
        uint2 u = *(const uint2*)(feat + s * 64 + fb);
        if (v) {
            s0 += bflo(u.x);
            s1 += bfhi(u.x);
            s2 += bflo(u.y);
            s3 += bfhi(u.y);
        }
    }
    s0 += __shfl_xor(s0, 16); s0 += __shfl_xor(s0, 32);
    s1 += __shfl_xor(s1, 16); s1 += __shfl_xor(s1, 32);
    s2 += __shfl_xor(s2, 16); s2 += __shfl_xor(s2, 32);
    s3 += __shfl_xor(s3, 16); s3 += __shfl_xor(s3, 32);
    if (l < 16) {
        float inv = 1.0f / fmaxf((float)deg, 1.0f);
        float m[4] = {s0 * inv, s1 * inv, s2 * inv, s3 * inv};
        ushort4 oh, ol;
        oh.x = f2bf(m[0]); ol.x = f2bf(m[0] - bf2f(oh.x));
        oh.y = f2bf(m[1]); ol.y = f2bf(m[1] - bf2f(oh.y));
        oh.z = f2bf(m[2]); ol.z = f2bf(m[2] - bf2f(oh.z));
        oh.w = f2bf(m[3]); ol.w = f2bf(m[3] - bf2f(oh.w));
        *(ushort4*)&mh[wid * 64 + fb] = oh;
        *(ushort4*)&ml[wid * 64 + fb] = ol;
    }
}

// Layer-1 overflow fix on split planes. Single block, serialized over edges
// (overflow is empty for this graph; correctness path only).
__global__ __launch_bounds__(64) void ovf_fix1_kernel(
        const unsigned short* __restrict__ xh, const int* __restrict__ ovf,
        const int* __restrict__ ovfc, const int* __restrict__ counts,
        unsigned short* __restrict__ mh, unsigned short* __restrict__ ml) {
    int n = *ovfc;
    if (n > OVF_CAP) n = OVF_CAP;
    int f = threadIdx.x;
    for (int idx = 0; idx < n; ++idx) {
        int s = ovf[idx * 2];
        int d = ovf[idx * 2 + 1];
        float inv = 1.0f / fmaxf((float)counts[d], 1.0f);
        float m = bf2f(mh[d * 64 + f]) + bf2f(ml[d * 64 + f])
                + bf2f(xh[s * 64 + f]) * inv;
        unsigned short vh = f2bf(m);
        mh[d * 64 + f] = vh;
        ml[d * 64 + f] = f2bf(m - bf2f(vh));
        __syncthreads();
    }
}

// Layer 1 MFMA: h = relu( [mean|x] @ [W1l;W1r] + b1 ), 3-term split product.
// All operands pre-split -> zero conversion VALU in the loop.
// Block = 64 rows; wave w owns col-tiles {2w,2w+1}, B resident in VGPRs.
__global__ __launch_bounds__(256) void l1_mfma_kernel(
        const unsigned short* __restrict__ mh, const unsigned short* __restrict__ ml,
        const unsigned short* __restrict__ xh, const unsigned short* __restrict__ xl,
        const short* __restrict__ Bf1, const float* __restrict__ b1,
        unsigned short* __restrict__ hh, unsigned short* __restrict__ hl) {
    const int w = threadIdx.x >> 6;
    const int l = threadIdx.x & 63;
    const int lane15 = l & 15;
    const int quad = l >> 4;
    const int rowBase = blockIdx.x * 64;

    bf16x8 bh[2][4], bl[2][4];
#pragma unroll
    for (int ci = 0; ci < 2; ++ci) {
        const int c = 2 * w + ci;
#pragma unroll
        for (int kc = 0; kc < 4; ++kc) {
            const short* bp = Bf1 + ((c * 4 + kc) * 2) * 512 + l * 8;
            bh[ci][kc] = *(const bf16x8*)bp;
            bl[ci][kc] = *(const bf16x8*)(bp + 512);
        }
    }
    float bias[2];
#pragma unroll
    for (int ci = 0; ci < 2; ++ci) bias[ci] = b1[(2 * w + ci) * 16 + lane15];

#pragma unroll
    for (int rt = 0; rt < 4; ++rt) {
        const int row = rowBase + rt * 16 + lane15;
        const bool rv = row < N_NODES;

        bf16x8 ah[4], al[4];
#pragma unroll
        for (int kc = 0; kc < 4; ++kc) {
            if (rv) {
                int off = (kc < 2) ? (row * 64 + kc * 32 + quad * 8)
                                   : (row * 64 + (kc - 2) * 32 + quad * 8);
                const unsigned short* ph = (kc < 2) ? (mh + off) : (xh + off);
                const unsigned short* pl = (kc < 2) ? (ml + off) : (xl + off);
                ah[kc] = *(const bf16x8*)ph;
                al[kc] = *(const bf16x8*)pl;
            } else {
                ah[kc] = (bf16x8)(short)0;
                al[kc] = (bf16x8)(short)0;
            }
        }

        f32x4 acc[2] = {(f32x4){0.f, 0.f, 0.f, 0.f}, (f32x4){0.f, 0.f, 0.f, 0.f}};
#pragma unroll
        for (int kc = 0; kc < 4; ++kc) {
#pragma unroll
            for (int ci = 0; ci < 2; ++ci) {
                acc[ci] = __builtin_amdgcn_mfma_f32_16x16x32_bf16(ah[kc], bh[ci][kc], acc[ci], 0, 0, 0);
                acc[ci] = __builtin_amdgcn_mfma_f32_16x16x32_bf16(al[kc], bh[ci][kc], acc[ci], 0, 0, 0);
                acc[ci] = __builtin_amdgcn_mfma_f32_16x16x32_bf16(ah[kc], bl[ci][kc], acc[ci], 0, 0, 0);
            }
        }

        const int rb = rowBase + rt * 16 + quad * 4;
#pragma unroll
        for (int ci = 0; ci < 2; ++ci) {
            const int col = (2 * w + ci) * 16 + lane15;
#pragma unroll
            for (int i = 0; i < 4; ++i) {
                int r = rb + i;
                if (r < N_NODES) {
                    float v = fmaxf(acc[ci][i] + bias[ci], 0.f);
                    unsigned short vh = f2bf(v);
                    hh[r * 128 + col] = vh;
                    hl[r * 128 + col] = f2bf(v - bf2f(vh));
                }
            }
        }
    }
}

// Layer 2 MFMA: p(bf16) = h @ W2l ; q(bf16) = h @ W2r + b2. 3-term.
__global__ __launch_bounds__(256) void l2_mfma_kernel(
        const unsigned short* __restrict__ hh, const unsigned short* __restrict__ hl,
        const short* __restrict__ Bf2, const float* __restrict__ b2,
        unsigned short* __restrict__ p_bf, unsigned short* __restrict__ qb) {
    const int w = threadIdx.x >> 6;
    const int l = threadIdx.x & 63;
    const int lane15 = l & 15;
    const int quad = l >> 4;
    const int rowBase = blockIdx.x * 64;

    bf16x8 bh[2][4], bl[2][4];
#pragma unroll
    for (int ci = 0; ci < 2; ++ci) {
        const int c = 2 * w + ci;
#pragma unroll
        for (int kc = 0; kc < 4; ++kc) {
            const short* bp = Bf2 + ((c * 4 + kc) * 2) * 512 + l * 8;
            bh[ci][kc] = *(const bf16x8*)bp;
            bl[ci][kc] = *(const bf16x8*)(bp + 512);
        }
    }
    float bias[2];
#pragma unroll
    for (int ci = 0; ci < 2; ++ci) {
        const int c = 2 * w + ci;
        bias[ci] = (c >= 4) ? b2[(c - 4) * 16 + lane15] : 0.f;
    }

#pragma unroll
    for (int rt = 0; rt < 4; ++rt) {
        const int row = rowBase + rt * 16 + lane15;
        const bool rv = row < N_NODES;

        bf16x8 ah[4], al[4];
#pragma unroll
        for (int kc = 0; kc < 4; ++kc) {
            if (rv) {
                int off = row * 128 + kc * 32 + quad * 8;
                ah[kc] = *(const bf16x8*)(hh + off);
                al[kc] = *(const bf16x8*)(hl + off);
            } else {
                ah[kc] = (bf16x8)(short)0;
                al[kc] = (bf16x8)(short)0;
            }
        }

        f32x4 acc[2] = {(f32x4){0.f, 0.f, 0.f, 0.f}, (f32x4){0.f, 0.f, 0.f, 0.f}};
#pragma unroll
        for (int kc = 0; kc < 4; ++kc) {
#pragma unroll
            for (int ci = 0; ci < 2; ++ci) {
                acc[ci] = __builtin_amdgcn_mfma_f32_16x16x32_bf16(ah[kc], bh[ci][kc], acc[ci], 0, 0, 0);
                acc[ci] = __builtin_amdgcn_mfma_f32_16x16x32_bf16(al[kc], bh[ci][kc], acc[ci], 0, 0, 0);
                acc[ci] = __builtin_amdgcn_mfma_f32_16x16x32_bf16(ah[kc], bl[ci][kc], acc[ci], 0, 0, 0);
            }
        }

        const int rb = rowBase + rt * 16 + quad * 4;
#pragma unroll
        for (int ci = 0; ci < 2; ++ci) {
            const int c = 2 * w + ci;
#pragma unroll
            for (int i = 0; i < 4; ++i) {
                int r = rb + i;
                if (r < N_NODES) {
                    if (c < 4)
                        p_bf[r * 64 + c * 16 + lane15] = f2bf(acc[ci][i]);
                    else
                        qb[r * 64 + (c - 4) * 16 + lane15] = f2bf(acc[ci][i] + bias[ci]);
                }
            }
        }
    }
}

// Fused layer-2 aggregation + epilogue: out = mean(p_bf[nbrs]) + q(bf16)
__global__ __launch_bounds__(256) void gather_final_kernel(
        const unsigned short* __restrict__ p, const int* __restrict__ counts,
        const int* __restrict__ slots, const unsigned short* __restrict__ qb,
        float* __restrict__ out) {
    int wid = blockIdx.x * 4 + (threadIdx.x >> 6);
    int l = threadIdx.x & 63;
    if (wid >= N_NODES) return;
    int deg = counts[wid];
    int dcap = min(deg, DEG_CAP);
    int ids = slots[wid * DEG_CAP + l];
    const int grp = l >> 4;
    const int fb = (l & 15) * 4;
    float s0 = 0.f, s1 = 0.f, s2 = 0.f, s3 = 0.f;
    int j = 0;
    for (; j + 8 <= dcap; j += 8) {
        int sA = __shfl(ids, j + grp);
        int sB = __shfl(ids, j + 4 + grp);
        uint2 uA = *(const uint2*)(p + sA * 64 + fb);
        uint2 uB = *(const uint2*)(p + sB * 64 + fb);
        s0 += bflo(uA.x) + bflo(uB.x);
        s1 += bfhi(uA.x) + bfhi(uB.x);
        s2 += bflo(uA.y) + bflo(uB.y);
        s3 += bfhi(uA.y) + bfhi(uB.y);
    }
    for (; j < dcap; j += 4) {
        int nb = j + grp;
        bool v = nb < dcap;
        int s = __shfl(ids, v ? nb : 0);
        uint2 u = *(const uint2*)(p + s * 64 + fb);
        if (v) {
            s0 += bflo(u.x);
            s1 += bfhi(u.x);
            s2 += bflo(u.y);
            s3 += bfhi(u.y);
        }
    }
    s0 += __shfl_xor(s0, 16); s0 += __shfl_xor(s0, 32);
    s1 += __shfl_xor(s1, 16); s1 += __shfl_xor(s1, 32);
    s2 += __shfl_xor(s2, 16); s2 += __shfl_xor(s2, 32);
    s3 += __shfl_xor(s3, 16); s3 += __shfl_xor(s3, 32);
    if (l < 16) {
        float inv = 1.0f / fmaxf((float)deg, 1.0f);
        ushort4 qv = *(const ushort4*)&qb[wid * 64 + fb];
        *(float4*)&out[wid * 64 + fb] =
            make_float4(s0 * inv + bf2f(qv.x), s1 * inv + bf2f(qv.y),
                        s2 * inv + bf2f(qv.z), s3 * inv + bf2f(qv.w));
    }
}

// Layer-2 overflow fix-up (additive, on fp32 out).
__global__ __launch_bounds__(64) void ovf_fixup_kernel(
        const unsigned short* __restrict__ p, const int* __restrict__ ovf,
        const int* __restrict__ ovfc, const int* __restrict__ counts,
        float* __restrict__ out) {
    int n = *ovfc;
    if (n > OVF_CAP) n = OVF_CAP;
    for (int idx = blockIdx.x; idx < n; idx += gridDim.x) {
        int s = ovf[idx * 2];
        int d = ovf[idx * 2 + 1];
        float inv = 1.0f / fmaxf((float)counts[d], 1.0f);
        atomicAdd(&out[d * 64 + threadIdx.x],
                  bf2f(p[s * 64 + threadIdx.x]) * inv);
    }
}

extern "C" void kernel_launch(void* const* d_in, const int* in_sizes, int n_in,
                              void* d_out, int out_size, void* d_ws, size_t ws_size,
                              hipStream_t stream) {
    const float* x   = (const float*)d_in[0];
    const float* W1l = (const float*)d_in[1];
    const float* W1r = (const float*)d_in[2];
    const float* b1  = (const float*)d_in[3];
    const float* W2l = (const float*)d_in[4];
    const float* W2r = (const float*)d_in[5];
    const float* b2  = (const float*)d_in[6];
    const int*   ei  = (const int*)d_in[7];

    int*   wsi      = (int*)d_ws;
    int*   counts_r = wsi;
    int*   bases_r  = wsi + 802816;
    int*   counts   = wsi + 1605632;
    unsigned short* pos16 = (unsigned short*)(wsi + 1705984);
    int*   ovfc     = wsi + 2205984;
    int*   ovf      = wsi + 2206048;
    short* Bf1      = (short*)(wsi + 2214240);
    short* Bf2      = (short*)(wsi + 2230624);
    int*   slots    = wsi + 2247008;
    unsigned short* xh    = (unsigned short*)(wsi + 8647008);
    unsigned short* xl    = (unsigned short*)(wsi + 11847008);
    unsigned short* meanh = (unsigned short*)(wsi + 15047008);
    unsigned short* meanl = (unsigned short*)(wsi + 18247008);
    unsigned short* p_bf  = meanh;   // reused after l1 consumes mean
    unsigned short* hh    = (unsigned short*)(wsi + 21447008);
    unsigned short* hl    = (unsigned short*)(wsi + 27847008);
    unsigned short* qb    = (unsigned short*)(wsi + 34247008);
    float* out      = (float*)d_out;

    prep_kernel<<<(N_NODES * 16 + 255) / 256, 256, 0, stream>>>(
        (const float4*)x, (ushort4*)xh, (ushort4*)xl,
        W1l, W1r, W2l, W2r, Bf1, Bf2, (int4*)counts_r, ovfc);
    hist_kernel<<<(N_EDGES + 255) / 256, 256, 0, stream>>>(ei, counts_r, pos16);
    scan_kernel<<<(N_NODES + 255) / 256, 256, 0, stream>>>(counts_r, bases_r, counts);
    fill_kernel<<<(N_EDGES + 255) / 256, 256, 0, stream>>>(
        ei, pos16, bases_r, slots, ovfc, ovf);

    // layer-1 aggregation -> mean split planes, + serialized overflow fix
    gather_bf_kernel<<<(N_NODES + 3) / 4, 256, 0, stream>>>(
        xh, counts, slots, meanh, meanl);
    ovf_fix1_kernel<<<1, 64, 0, stream>>>(xh, ovf, ovfc, counts, meanh, meanl);

    // h = relu([mean|x] @ [W1l;W1r] + b1) -> split planes
    l1_mfma_kernel<<<(N_NODES + 63) / 64, 256, 0, stream>>>(
        meanh, meanl, xh, xl, Bf1, b1, hh, hl);
    // p(bf16) = h @ W2l ; q(bf16) = h @ W2r + b2   (p_bf overwrites meanh)
    l2_mfma_kernel<<<(N_NODES + 63) / 64, 256, 0, stream>>>(
        hh, hl, Bf2, b2, p_bf, qb);

    // fused layer-2 aggregation + epilogue, then overflow fix-up
    gather_final_kernel<<<(N_NODES + 3) / 4, 256, 0, stream>>>(
        p_bf, counts, slots, qb, out);
    ovf_fixup_kernel<<<64, 64, 0, stream>>>(p_bf, ovf, ovfc, counts, out);
}